// Round 1
// baseline (1629.231 us; speedup 1.0000x reference)
//
#include <hip/hip_runtime.h>
#include <float.h>
#include <math.h>

#define P_DIM 24960
#define N_DB  6000

// ---------------------------------------------------------------- zero
__global__ __launch_bounds__(256) void zero_kernel(float* __restrict__ p, int n) {
    int i = blockIdx.x * 256 + threadIdx.x;
    if (i < n) p[i] = 0.f;
}

// ---------------------------------------------------------------- NN GEMM, M=64, atomic k-split
// C[64 x N] += A[64 x K] @ B[K x N].  Tile 64x64x64.  grid.x = N/64, grid.y = ksplit
__global__ __launch_bounds__(256) void gemm_nn_a64_atomic(
    const float* __restrict__ A, const float* __restrict__ B, float* __restrict__ C,
    int lda, int ldb, int ldc, int ktiles)
{
    __shared__ float As[64][66];   // [m][kk], pad 66 -> b64-mergeable reads
    __shared__ float Bs[64][68];   // [kk][nn], pad 68 -> aligned float4 reads
    const int t = threadIdx.x;
    const int tx = t & 15, ty = t >> 4;
    const int n0 = blockIdx.x * 64;
    const int kbase = blockIdx.y * ktiles * 64;
    const int kk = t & 63, r = t >> 6;
    float acc[4][4] = {};
    for (int kt = 0; kt < ktiles; ++kt) {
        const int k0 = kbase + kt * 64;
        #pragma unroll
        for (int i = 0; i < 16; ++i) {
            const int m = r + i * 4;
            As[m][kk] = A[m * lda + k0 + kk];
        }
        #pragma unroll
        for (int i = 0; i < 16; ++i) {
            const int krow = r + i * 4;
            Bs[krow][kk] = B[(size_t)(k0 + krow) * ldb + n0 + kk];
        }
        __syncthreads();
        #pragma unroll 16
        for (int k2 = 0; k2 < 64; ++k2) {
            const float4 bv = *(const float4*)&Bs[k2][tx * 4];
            #pragma unroll
            for (int i = 0; i < 4; ++i) {
                const float av = As[ty * 4 + i][k2];
                acc[i][0] += av * bv.x;
                acc[i][1] += av * bv.y;
                acc[i][2] += av * bv.z;
                acc[i][3] += av * bv.w;
            }
        }
        __syncthreads();
    }
    #pragma unroll
    for (int i = 0; i < 4; ++i)
        #pragma unroll
        for (int j = 0; j < 4; ++j)
            atomicAdd(&C[(ty * 4 + i) * ldc + n0 + tx * 4 + j], acc[i][j]);
}

// ---------------------------------------------------------------- scores = ||f_j||^2 - 2*cls@F^T
// grid.x = ceil(6000/64). sqrt + ||cls||^2 omitted (monotone / row-constant).
__global__ __launch_bounds__(256) void score_gemm_nt(
    const float* __restrict__ cls, const float* __restrict__ F,
    float* __restrict__ scores)
{
    __shared__ float As[64][66];   // cls  [m][kk]
    __shared__ float Bs[64][66];   // F rows [jj][kk]
    __shared__ float fns[64];
    const int t = threadIdx.x, tx = t & 15, ty = t >> 4;
    const int j0 = blockIdx.x * 64;
    const int kk = t & 63, r = t >> 6;
    float acc[4][4] = {};
    float fn = 0.f;
    for (int k0 = 0; k0 < 512; k0 += 64) {
        #pragma unroll
        for (int i = 0; i < 16; ++i) {
            const int m = r + i * 4;
            As[m][kk] = cls[m * 512 + k0 + kk];
        }
        #pragma unroll
        for (int i = 0; i < 16; ++i) {
            const int jj = r + i * 4;
            const int j = j0 + jj;
            Bs[jj][kk] = (j < N_DB) ? F[(size_t)j * 512 + k0 + kk] : 0.f;
        }
        __syncthreads();
        if (t < 64) {
            float sloc = 0.f;
            #pragma unroll 16
            for (int k2 = 0; k2 < 64; ++k2) sloc += Bs[t][k2] * Bs[t][k2];
            fn += sloc;
        }
        #pragma unroll 16
        for (int k2 = 0; k2 < 64; ++k2) {
            float a[4], bb[4];
            #pragma unroll
            for (int i = 0; i < 4; ++i) a[i] = As[ty * 4 + i][k2];
            #pragma unroll
            for (int j = 0; j < 4; ++j) bb[j] = Bs[tx * 4 + j][k2];
            #pragma unroll
            for (int i = 0; i < 4; ++i)
                #pragma unroll
                for (int j = 0; j < 4; ++j) acc[i][j] += a[i] * bb[j];
        }
        __syncthreads();
    }
    if (t < 64) fns[t] = fn;
    __syncthreads();
    #pragma unroll
    for (int i = 0; i < 4; ++i)
        #pragma unroll
        for (int j = 0; j < 4; ++j) {
            const int jcol = j0 + tx * 4 + j;
            if (jcol < N_DB)
                scores[(ty * 4 + i) * N_DB + jcol] = fns[tx * 4 + j] - 2.f * acc[i][j];
        }
}

// ---------------------------------------------------------------- top-10 argmin per row (64 blocks)
__global__ __launch_bounds__(256) void topk_kernel(const float* __restrict__ scores,
                                                   int* __restrict__ topk)
{
    __shared__ float sc[N_DB];
    __shared__ float rv[256];
    __shared__ int   ri[256];
    const int b = blockIdx.x, t = threadIdx.x;
    for (int i = t; i < N_DB; i += 256) sc[i] = scores[b * N_DB + i];
    __syncthreads();
    for (int k = 0; k < 10; ++k) {
        float bv = FLT_MAX; int bi = 0x7fffffff;
        for (int i = t; i < N_DB; i += 256) {
            float v = sc[i];
            if (v < bv) { bv = v; bi = i; }
        }
        rv[t] = bv; ri[t] = bi;
        __syncthreads();
        for (int s = 128; s > 0; s >>= 1) {
            if (t < s) {
                if (rv[t + s] < rv[t] || (rv[t + s] == rv[t] && ri[t + s] < ri[t])) {
                    rv[t] = rv[t + s]; ri[t] = ri[t + s];
                }
            }
            __syncthreads();
        }
        if (t == 0) { topk[b * 10 + k] = ri[0]; sc[ri[0]] = FLT_MAX; }
        __syncthreads();
    }
}

// ---------------------------------------------------------------- normalize + patchify + linear + cls tok
__global__ __launch_bounds__(384) void patch_embed_kernel(
    const float* __restrict__ x, const float* __restrict__ W_patch,
    const float* __restrict__ cls_tok, float* __restrict__ embed)
{
    __shared__ float Pp[64][49];   // [patch][48], pad
    const int b = blockIdx.x, t = threadIdx.x;
    const float mean[3] = {0.4914f, 0.4822f, 0.4465f};
    const float stdv[3] = {0.2470f, 0.2435f, 0.2616f};
    for (int u = t; u < 3072; u += 384) {
        const int c = u >> 10, rem = u & 1023, row = rem >> 5, col = rem & 31;
        const float v = (x[b * 3072 + u] - mean[c]) / stdv[c];
        const int pi = (row >> 2) * 8 + (col >> 2);
        const int rr = c * 16 + (row & 3) * 4 + (col & 3);
        Pp[pi][rr] = v;
    }
    // W_patch column t hoisted to registers (reused by all 64 patches)
    float wcol[48];
    #pragma unroll
    for (int rr = 0; rr < 48; ++rr) wcol[rr] = W_patch[rr * 384 + t];
    __syncthreads();
    float* erow = embed + (size_t)b * P_DIM;
    erow[t] = cls_tok[t];          // token 0
    for (int pi = 0; pi < 64; ++pi) {
        float acc = 0.f;
        #pragma unroll
        for (int rr = 0; rr < 48; ++rr) acc += Pp[pi][rr] * wcol[rr];
        erow[(1 + pi) * 384 + t] = acc;
    }
}

// ---------------------------------------------------------------- t = q @ Wk^T  (NT, grid = 24960/64 = 390)
__global__ __launch_bounds__(256) void gemm_nt_t(
    const float* __restrict__ q, const float* __restrict__ Wk, float* __restrict__ tmat)
{
    __shared__ float As[64][66];
    __shared__ float Bs[64][66];
    const int t = threadIdx.x, tx = t & 15, ty = t >> 4;
    const int p0 = blockIdx.x * 64;
    const int kk = t & 63, r = t >> 6;
    float acc[4][4] = {};
    for (int k0 = 0; k0 < 2048; k0 += 64) {
        #pragma unroll
        for (int i = 0; i < 16; ++i) {
            const int m = r + i * 4;
            As[m][kk] = q[m * 2048 + k0 + kk];
        }
        #pragma unroll
        for (int i = 0; i < 16; ++i) {
            const int pp = r + i * 4;
            Bs[pp][kk] = Wk[(size_t)(p0 + pp) * 2048 + k0 + kk];
        }
        __syncthreads();
        #pragma unroll 16
        for (int k2 = 0; k2 < 64; ++k2) {
            float a[4], bb[4];
            #pragma unroll
            for (int i = 0; i < 4; ++i) a[i] = As[ty * 4 + i][k2];
            #pragma unroll
            for (int j = 0; j < 4; ++j) bb[j] = Bs[tx * 4 + j][k2];
            #pragma unroll
            for (int i = 0; i < 4; ++i)
                #pragma unroll
                for (int j = 0; j < 4; ++j) acc[i][j] += a[i] * bb[j];
        }
        __syncthreads();
    }
    #pragma unroll
    for (int i = 0; i < 4; ++i) {
        float4 v = make_float4(acc[i][0], acc[i][1], acc[i][2], acc[i][3]);
        *(float4*)&tmat[(size_t)(ty * 4 + i) * P_DIM + p0 + tx * 4] = v;
    }
}

// ---------------------------------------------------------------- s[b,n] = dot(neighbor_row, t_b)
__global__ __launch_bounds__(256) void sdot_kernel(
    const float* __restrict__ OTin, const float* __restrict__ OTout,
    const int* __restrict__ topk, const float* __restrict__ tmat,
    float* __restrict__ s)
{
    const int n = blockIdx.x;   // 0..19
    const int b = blockIdx.y;   // 0..63
    const int t = threadIdx.x;
    const int id = topk[b * 10 + (n % 10)];
    const float4* row = (const float4*)((n < 10 ? OTin : OTout) + (size_t)id * P_DIM);
    const float4* tr  = (const float4*)(tmat + (size_t)b * P_DIM);
    float acc = 0.f;
    for (int i = t; i < P_DIM / 4; i += 256) {
        float4 a = row[i], c = tr[i];
        acc += a.x * c.x + a.y * c.y + a.z * c.z + a.w * c.w;
    }
    __shared__ float red[256];
    red[t] = acc; __syncthreads();
    for (int st = 128; st > 0; st >>= 1) {
        if (t < st) red[t] += red[t + st];
        __syncthreads();
    }
    if (t == 0) s[b * 20 + n] = red[0];
}

// ---------------------------------------------------------------- softmax over 20 neighbors
__global__ __launch_bounds__(64) void softmax_kernel(const float* __restrict__ s,
                                                     float* __restrict__ attn)
{
    const int b = threadIdx.x;   // 64 threads, one per batch row
    const float scale = 0.02209708691207961f;   // 1/sqrt(2048)
    float l[20]; float m = -FLT_MAX;
    #pragma unroll
    for (int n = 0; n < 20; ++n) { l[n] = s[b * 20 + n] * scale; m = fmaxf(m, l[n]); }
    float sum = 0.f;
    #pragma unroll
    for (int n = 0; n < 20; ++n) { l[n] = expf(l[n] - m); sum += l[n]; }
    const float inv = 1.f / sum;
    #pragma unroll
    for (int n = 0; n < 20; ++n) attn[b * 20 + n] = l[n] * inv;
}

// ---------------------------------------------------------------- out[b,:] = sum_n attn[b,n]*row_n
__global__ __launch_bounds__(256) void out_kernel(
    const float* __restrict__ OTin, const float* __restrict__ OTout,
    const int* __restrict__ topk, const float* __restrict__ attn,
    float* __restrict__ out)
{
    const int pt = blockIdx.x;   // 0..9 : chunk of 624 float4 (2496 floats)
    const int b  = blockIdx.y;
    const int t  = threadIdx.x;
    __shared__ float aw[20];
    __shared__ const float4* rows[20];
    if (t < 20) {
        const int id = topk[b * 10 + (t % 10)];
        rows[t] = (const float4*)((t < 10 ? OTin : OTout) + (size_t)id * P_DIM) + pt * 624;
        aw[t] = attn[b * 20 + t];
    }
    __syncthreads();
    float4* outp = (float4*)(out + (size_t)b * P_DIM) + pt * 624;
    for (int i = t; i < 624; i += 256) {
        float4 acc = make_float4(0.f, 0.f, 0.f, 0.f);
        #pragma unroll
        for (int n = 0; n < 20; ++n) {
            const float4 v = rows[n][i];
            const float w = aw[n];
            acc.x += w * v.x; acc.y += w * v.y; acc.z += w * v.z; acc.w += w * v.w;
        }
        outp[i] = acc;
    }
}

// ================================================================ launch
extern "C" void kernel_launch(void* const* d_in, const int* in_sizes, int n_in,
                              void* d_out, int out_size, void* d_ws, size_t ws_size,
                              hipStream_t stream)
{
    const float* x     = (const float*)d_in[0];   // [64,3,32,32]
    const float* dml   = (const float*)d_in[1];   // [6000,512]
    const float* OTin  = (const float*)d_in[2];   // [6000,24960]
    const float* OTout = (const float*)d_in[3];   // [6000,24960]
    const float* Wd    = (const float*)d_in[4];   // [3072,512]
    const float* Wp    = (const float*)d_in[5];   // [48,384]
    const float* ct    = (const float*)d_in[6];   // [384]
    const float* Wq    = (const float*)d_in[7];   // [24960,2048]
    const float* Wk    = (const float*)d_in[8];   // [24960,2048]
    float* out = (float*)d_out;                   // [64,65,384] = [64,24960]

    char* ws = (char*)d_ws;
    float* cls    = (float*)(ws + 0);         //  64*512
    float* scores = (float*)(ws + 131072);    //  64*6000
    int*   topk   = (int*)  (ws + 1667072);   //  64*10
    float* embed  = (float*)(ws + 1669632);   //  64*24960
    float* q      = (float*)(ws + 8059392);   //  64*2048
    float* tmat   = (float*)(ws + 8583680);   //  64*24960
    float* s      = (float*)(ws + 14973440);  //  64*20
    float* attn   = (float*)(ws + 14978560);  //  64*20

    // zero atomic-accumulated outputs (ws is poisoned 0xAA every call)
    zero_kernel<<<dim3(128), 256, 0, stream>>>(cls, 64 * 512);
    zero_kernel<<<dim3(512), 256, 0, stream>>>(q, 64 * 2048);

    // 1. cls = x @ W_dml       [64,3072]@[3072,512]; 48 ktiles, 16-way ksplit
    gemm_nn_a64_atomic<<<dim3(8, 16), 256, 0, stream>>>(x, Wd, cls, 3072, 512, 512, 3);
    // 2. scores[b,j] = ||f_j||^2 - 2 cls_b.f_j
    score_gemm_nt<<<dim3(94), 256, 0, stream>>>(cls, dml, scores);
    // 3. top-10 smallest per row
    topk_kernel<<<dim3(64), 256, 0, stream>>>(scores, topk);
    // 4. embed = patch_embed(x)
    patch_embed_kernel<<<dim3(64), 384, 0, stream>>>(x, Wp, ct, embed);
    // 5. q = embed @ Wq        [64,24960]@[24960,2048]; 390 ktiles, 13-way ksplit
    gemm_nn_a64_atomic<<<dim3(32, 13), 256, 0, stream>>>(embed, Wq, q, P_DIM, 2048, 2048, 30);
    // 6. t = q @ Wk^T          (replaces the 131-GFLOP neighbors@Wk einsum)
    gemm_nt_t<<<dim3(390), 256, 0, stream>>>(q, Wk, tmat);
    // 7. s[b,n] = nb_bn . t_b
    sdot_kernel<<<dim3(20, 64), 256, 0, stream>>>(OTin, OTout, topk, tmat, s);
    // 8. attn = softmax(s / sqrt(2048))
    softmax_kernel<<<dim3(1), 64, 0, stream>>>(s, attn);
    // 9. out = attn-weighted sum of neighbor rows
    out_kernel<<<dim3(10, 64), 256, 0, stream>>>(OTin, OTout, topk, attn, out);
}

// Round 2
// 1522.347 us; speedup vs baseline: 1.0702x; 1.0702x over previous
//
#include <hip/hip_runtime.h>
#include <float.h>
#include <math.h>

#define P_DIM 24960
#define N_DB  6000

typedef __bf16 bf16x8 __attribute__((ext_vector_type(8)));
typedef float  floatx4 __attribute__((ext_vector_type(4)));

// round-to-nearest-even fp32 -> bf16, packed pair -> u32 (lo | hi<<16)
static __device__ __forceinline__ unsigned f2bf_pk(float lo, float hi) {
    unsigned a = __builtin_bit_cast(unsigned, lo);
    unsigned b = __builtin_bit_cast(unsigned, hi);
    a = (a + 0x7FFFu + ((a >> 16) & 1u)) >> 16;
    b = (b + 0x7FFFu + ((b >> 16) & 1u)) & 0xFFFF0000u;
    return a | b;
}

// ---------------------------------------------------------------- zero
__global__ __launch_bounds__(256) void zero_kernel(float* __restrict__ p, int n) {
    int i = blockIdx.x * 256 + threadIdx.x;
    if (i < n) p[i] = 0.f;
}

// ---------------------------------------------------------------- MFMA GEMM (NN): C[64xN] += A[64xK] @ B[KxN]
// bf16 MFMA 16x16x32, fp32 inputs converted during LDS staging.
// grid = (N/64, ksplit), block 256. C accumulated via atomicAdd (pre-zeroed).
__global__ __launch_bounds__(256) void gemm_nn_mfma(
    const float* __restrict__ A, const float* __restrict__ B, float* __restrict__ C,
    int K, int ldb, int ldc, int ktiles)
{
    __shared__ __align__(16) unsigned short Asl[64][72];  // [m][k] bf16, pitch 72 (odd*16B)
    __shared__ __align__(16) unsigned short Bsl[64][72];  // [n][k] bf16 (transposed on stage)
    const int t    = threadIdx.x;
    const int wave = t >> 6;          // m-block 0..3
    const int lane = t & 63;
    const int lm   = lane & 15;
    const int quad = lane >> 4;
    const int n0   = blockIdx.x * 64;
    const int kbase = blockIdx.y * ktiles * 64;

    floatx4 acc[4] = {};              // 4 n-blocks of 16
    const int am  = t >> 4;           // A-stage row base (0..15)
    const int ak4 = (t & 15) * 4;     // A-stage k offset
    const int bn  = t & 63;           // B-stage column
    const int br  = t >> 6;           // B-stage k-row group

    for (int kt = 0; kt < ktiles; ++kt) {
        const int k0 = kbase + kt * 64;
        // stage A: 4 rows x float4 per thread, convert, b64 write
        #pragma unroll
        for (int i = 0; i < 4; ++i) {
            const int m = am + i * 16;
            const float4 v = *(const float4*)&A[(size_t)m * K + k0 + ak4];
            uint2 p; p.x = f2bf_pk(v.x, v.y); p.y = f2bf_pk(v.z, v.w);
            *(uint2*)&Asl[m][ak4] = p;
        }
        // stage B transposed: column bn, 4 k-quads per thread
        #pragma unroll
        for (int i = 0; i < 4; ++i) {
            const int kq = br * 16 + i * 4;
            float v0 = B[(size_t)(k0 + kq + 0) * ldb + n0 + bn];
            float v1 = B[(size_t)(k0 + kq + 1) * ldb + n0 + bn];
            float v2 = B[(size_t)(k0 + kq + 2) * ldb + n0 + bn];
            float v3 = B[(size_t)(k0 + kq + 3) * ldb + n0 + bn];
            uint2 p; p.x = f2bf_pk(v0, v1); p.y = f2bf_pk(v2, v3);
            *(uint2*)&Bsl[bn][kq] = p;
        }
        __syncthreads();
        #pragma unroll
        for (int s = 0; s < 2; ++s) {
            const bf16x8 av = *(const bf16x8*)&Asl[wave * 16 + lm][s * 32 + quad * 8];
            #pragma unroll
            for (int nb = 0; nb < 4; ++nb) {
                const bf16x8 bv = *(const bf16x8*)&Bsl[nb * 16 + lm][s * 32 + quad * 8];
                acc[nb] = __builtin_amdgcn_mfma_f32_16x16x32_bf16(av, bv, acc[nb], 0, 0, 0);
            }
        }
        __syncthreads();
    }
    const int rbase = wave * 16 + quad * 4;
    #pragma unroll
    for (int nb = 0; nb < 4; ++nb) {
        const int col = n0 + nb * 16 + lm;
        #pragma unroll
        for (int r = 0; r < 4; ++r)
            atomicAdd(&C[(size_t)(rbase + r) * ldc + col], acc[nb][r]);
    }
}

// ---------------------------------------------------------------- MFMA GEMM (NT): C[64xN] = A[64xK] @ Brows[NxK]^T
// grid = N/64, block 256, K multiple of 64, direct stores.
__global__ __launch_bounds__(256) void gemm_nt_mfma(
    const float* __restrict__ A, const float* __restrict__ Brows, float* __restrict__ C,
    int K, int ldc)
{
    __shared__ __align__(16) unsigned short Asl[64][72];
    __shared__ __align__(16) unsigned short Bsl[64][72];
    const int t    = threadIdx.x;
    const int wave = t >> 6;
    const int lane = t & 63;
    const int lm   = lane & 15;
    const int quad = lane >> 4;
    const int p0   = blockIdx.x * 64;

    floatx4 acc[4] = {};
    const int am  = t >> 4;
    const int ak4 = (t & 15) * 4;

    for (int k0 = 0; k0 < K; k0 += 64) {
        #pragma unroll
        for (int i = 0; i < 4; ++i) {
            const int m = am + i * 16;
            const float4 va = *(const float4*)&A[(size_t)m * K + k0 + ak4];
            uint2 pa; pa.x = f2bf_pk(va.x, va.y); pa.y = f2bf_pk(va.z, va.w);
            *(uint2*)&Asl[m][ak4] = pa;
            const float4 vb = *(const float4*)&Brows[(size_t)(p0 + m) * K + k0 + ak4];
            uint2 pb; pb.x = f2bf_pk(vb.x, vb.y); pb.y = f2bf_pk(vb.z, vb.w);
            *(uint2*)&Bsl[m][ak4] = pb;
        }
        __syncthreads();
        #pragma unroll
        for (int s = 0; s < 2; ++s) {
            const bf16x8 av = *(const bf16x8*)&Asl[wave * 16 + lm][s * 32 + quad * 8];
            #pragma unroll
            for (int nb = 0; nb < 4; ++nb) {
                const bf16x8 bv = *(const bf16x8*)&Bsl[nb * 16 + lm][s * 32 + quad * 8];
                acc[nb] = __builtin_amdgcn_mfma_f32_16x16x32_bf16(av, bv, acc[nb], 0, 0, 0);
            }
        }
        __syncthreads();
    }
    const int rbase = wave * 16 + quad * 4;
    #pragma unroll
    for (int nb = 0; nb < 4; ++nb) {
        const int col = p0 + nb * 16 + lm;
        #pragma unroll
        for (int r = 0; r < 4; ++r)
            C[(size_t)(rbase + r) * ldc + col] = acc[nb][r];
    }
}

// ---------------------------------------------------------------- fp32 NN GEMM (kept for the small cls GEMM; retrieval must stay fp32)
__global__ __launch_bounds__(256) void gemm_nn_a64_atomic(
    const float* __restrict__ A, const float* __restrict__ B, float* __restrict__ C,
    int lda, int ldb, int ldc, int ktiles)
{
    __shared__ float As[64][66];
    __shared__ float Bs[64][68];
    const int t = threadIdx.x;
    const int tx = t & 15, ty = t >> 4;
    const int n0 = blockIdx.x * 64;
    const int kbase = blockIdx.y * ktiles * 64;
    const int kk = t & 63, r = t >> 6;
    float acc[4][4] = {};
    for (int kt = 0; kt < ktiles; ++kt) {
        const int k0 = kbase + kt * 64;
        #pragma unroll
        for (int i = 0; i < 16; ++i) {
            const int m = r + i * 4;
            As[m][kk] = A[m * lda + k0 + kk];
        }
        #pragma unroll
        for (int i = 0; i < 16; ++i) {
            const int krow = r + i * 4;
            Bs[krow][kk] = B[(size_t)(k0 + krow) * ldb + n0 + kk];
        }
        __syncthreads();
        #pragma unroll 16
        for (int k2 = 0; k2 < 64; ++k2) {
            const float4 bv = *(const float4*)&Bs[k2][tx * 4];
            #pragma unroll
            for (int i = 0; i < 4; ++i) {
                const float av = As[ty * 4 + i][k2];
                acc[i][0] += av * bv.x;
                acc[i][1] += av * bv.y;
                acc[i][2] += av * bv.z;
                acc[i][3] += av * bv.w;
            }
        }
        __syncthreads();
    }
    #pragma unroll
    for (int i = 0; i < 4; ++i)
        #pragma unroll
        for (int j = 0; j < 4; ++j)
            atomicAdd(&C[(ty * 4 + i) * ldc + n0 + tx * 4 + j], acc[i][j]);
}

// ---------------------------------------------------------------- scores = ||f_j||^2 - 2*cls@F^T  (fp32, unchanged)
__global__ __launch_bounds__(256) void score_gemm_nt(
    const float* __restrict__ cls, const float* __restrict__ F,
    float* __restrict__ scores)
{
    __shared__ float As[64][66];
    __shared__ float Bs[64][66];
    __shared__ float fns[64];
    const int t = threadIdx.x, tx = t & 15, ty = t >> 4;
    const int j0 = blockIdx.x * 64;
    const int kk = t & 63, r = t >> 6;
    float acc[4][4] = {};
    float fn = 0.f;
    for (int k0 = 0; k0 < 512; k0 += 64) {
        #pragma unroll
        for (int i = 0; i < 16; ++i) {
            const int m = r + i * 4;
            As[m][kk] = cls[m * 512 + k0 + kk];
        }
        #pragma unroll
        for (int i = 0; i < 16; ++i) {
            const int jj = r + i * 4;
            const int j = j0 + jj;
            Bs[jj][kk] = (j < N_DB) ? F[(size_t)j * 512 + k0 + kk] : 0.f;
        }
        __syncthreads();
        if (t < 64) {
            float sloc = 0.f;
            #pragma unroll 16
            for (int k2 = 0; k2 < 64; ++k2) sloc += Bs[t][k2] * Bs[t][k2];
            fn += sloc;
        }
        #pragma unroll 16
        for (int k2 = 0; k2 < 64; ++k2) {
            float a[4], bb[4];
            #pragma unroll
            for (int i = 0; i < 4; ++i) a[i] = As[ty * 4 + i][k2];
            #pragma unroll
            for (int j = 0; j < 4; ++j) bb[j] = Bs[tx * 4 + j][k2];
            #pragma unroll
            for (int i = 0; i < 4; ++i)
                #pragma unroll
                for (int j = 0; j < 4; ++j) acc[i][j] += a[i] * bb[j];
        }
        __syncthreads();
    }
    if (t < 64) fns[t] = fn;
    __syncthreads();
    #pragma unroll
    for (int i = 0; i < 4; ++i)
        #pragma unroll
        for (int j = 0; j < 4; ++j) {
            const int jcol = j0 + tx * 4 + j;
            if (jcol < N_DB)
                scores[(ty * 4 + i) * N_DB + jcol] = fns[tx * 4 + j] - 2.f * acc[i][j];
        }
}

// ---------------------------------------------------------------- top-10 argmin per row
__global__ __launch_bounds__(256) void topk_kernel(const float* __restrict__ scores,
                                                   int* __restrict__ topk)
{
    __shared__ float sc[N_DB];
    __shared__ float rv[256];
    __shared__ int   ri[256];
    const int b = blockIdx.x, t = threadIdx.x;
    for (int i = t; i < N_DB; i += 256) sc[i] = scores[b * N_DB + i];
    __syncthreads();
    for (int k = 0; k < 10; ++k) {
        float bv = FLT_MAX; int bi = 0x7fffffff;
        for (int i = t; i < N_DB; i += 256) {
            float v = sc[i];
            if (v < bv) { bv = v; bi = i; }
        }
        rv[t] = bv; ri[t] = bi;
        __syncthreads();
        for (int s = 128; s > 0; s >>= 1) {
            if (t < s) {
                if (rv[t + s] < rv[t] || (rv[t + s] == rv[t] && ri[t + s] < ri[t])) {
                    rv[t] = rv[t + s]; ri[t] = ri[t + s];
                }
            }
            __syncthreads();
        }
        if (t == 0) { topk[b * 10 + k] = ri[0]; sc[ri[0]] = FLT_MAX; }
        __syncthreads();
    }
}

// ---------------------------------------------------------------- normalize + patchify + linear + cls tok
__global__ __launch_bounds__(384) void patch_embed_kernel(
    const float* __restrict__ x, const float* __restrict__ W_patch,
    const float* __restrict__ cls_tok, float* __restrict__ embed)
{
    __shared__ float Pp[64][49];
    const int b = blockIdx.x, t = threadIdx.x;
    const float mean[3] = {0.4914f, 0.4822f, 0.4465f};
    const float stdv[3] = {0.2470f, 0.2435f, 0.2616f};
    for (int u = t; u < 3072; u += 384) {
        const int c = u >> 10, rem = u & 1023, row = rem >> 5, col = rem & 31;
        const float v = (x[b * 3072 + u] - mean[c]) / stdv[c];
        const int pi = (row >> 2) * 8 + (col >> 2);
        const int rr = c * 16 + (row & 3) * 4 + (col & 3);
        Pp[pi][rr] = v;
    }
    float wcol[48];
    #pragma unroll
    for (int rr = 0; rr < 48; ++rr) wcol[rr] = W_patch[rr * 384 + t];
    __syncthreads();
    float* erow = embed + (size_t)b * P_DIM;
    erow[t] = cls_tok[t];
    for (int pi = 0; pi < 64; ++pi) {
        float acc = 0.f;
        #pragma unroll
        for (int rr = 0; rr < 48; ++rr) acc += Pp[pi][rr] * wcol[rr];
        erow[(1 + pi) * 384 + t] = acc;
    }
}

// ---------------------------------------------------------------- s[b,n] = dot(neighbor_row, t_b)
__global__ __launch_bounds__(256) void sdot_kernel(
    const float* __restrict__ OTin, const float* __restrict__ OTout,
    const int* __restrict__ topk, const float* __restrict__ tmat,
    float* __restrict__ s)
{
    const int n = blockIdx.x;
    const int b = blockIdx.y;
    const int t = threadIdx.x;
    const int id = topk[b * 10 + (n % 10)];
    const float4* row = (const float4*)((n < 10 ? OTin : OTout) + (size_t)id * P_DIM);
    const float4* tr  = (const float4*)(tmat + (size_t)b * P_DIM);
    float acc = 0.f;
    for (int i = t; i < P_DIM / 4; i += 256) {
        float4 a = row[i], c = tr[i];
        acc += a.x * c.x + a.y * c.y + a.z * c.z + a.w * c.w;
    }
    __shared__ float red[256];
    red[t] = acc; __syncthreads();
    for (int st = 128; st > 0; st >>= 1) {
        if (t < st) red[t] += red[t + st];
        __syncthreads();
    }
    if (t == 0) s[b * 20 + n] = red[0];
}

// ---------------------------------------------------------------- softmax over 20 neighbors
__global__ __launch_bounds__(64) void softmax_kernel(const float* __restrict__ s,
                                                     float* __restrict__ attn)
{
    const int b = threadIdx.x;
    const float scale = 0.02209708691207961f;
    float l[20]; float m = -FLT_MAX;
    #pragma unroll
    for (int n = 0; n < 20; ++n) { l[n] = s[b * 20 + n] * scale; m = fmaxf(m, l[n]); }
    float sum = 0.f;
    #pragma unroll
    for (int n = 0; n < 20; ++n) { l[n] = expf(l[n] - m); sum += l[n]; }
    const float inv = 1.f / sum;
    #pragma unroll
    for (int n = 0; n < 20; ++n) attn[b * 20 + n] = l[n] * inv;
}

// ---------------------------------------------------------------- out[b,:] = sum_n attn[b,n]*row_n
__global__ __launch_bounds__(256) void out_kernel(
    const float* __restrict__ OTin, const float* __restrict__ OTout,
    const int* __restrict__ topk, const float* __restrict__ attn,
    float* __restrict__ out)
{
    const int pt = blockIdx.x;
    const int b  = blockIdx.y;
    const int t  = threadIdx.x;
    __shared__ float aw[20];
    __shared__ const float4* rows[20];
    if (t < 20) {
        const int id = topk[b * 10 + (t % 10)];
        rows[t] = (const float4*)((t < 10 ? OTin : OTout) + (size_t)id * P_DIM) + pt * 624;
        aw[t] = attn[b * 20 + t];
    }
    __syncthreads();
    float4* outp = (float4*)(out + (size_t)b * P_DIM) + pt * 624;
    for (int i = t; i < 624; i += 256) {
        float4 acc = make_float4(0.f, 0.f, 0.f, 0.f);
        #pragma unroll
        for (int n = 0; n < 20; ++n) {
            const float4 v = rows[n][i];
            const float w = aw[n];
            acc.x += w * v.x; acc.y += w * v.y; acc.z += w * v.z; acc.w += w * v.w;
        }
        outp[i] = acc;
    }
}

// ================================================================ launch
extern "C" void kernel_launch(void* const* d_in, const int* in_sizes, int n_in,
                              void* d_out, int out_size, void* d_ws, size_t ws_size,
                              hipStream_t stream)
{
    const float* x     = (const float*)d_in[0];
    const float* dml   = (const float*)d_in[1];
    const float* OTin  = (const float*)d_in[2];
    const float* OTout = (const float*)d_in[3];
    const float* Wd    = (const float*)d_in[4];
    const float* Wp    = (const float*)d_in[5];
    const float* ct    = (const float*)d_in[6];
    const float* Wq    = (const float*)d_in[7];
    const float* Wk    = (const float*)d_in[8];
    float* out = (float*)d_out;

    char* ws = (char*)d_ws;
    float* cls    = (float*)(ws + 0);
    float* scores = (float*)(ws + 131072);
    int*   topk   = (int*)  (ws + 1667072);
    float* embed  = (float*)(ws + 1669632);
    float* q      = (float*)(ws + 8059392);
    float* tmat   = (float*)(ws + 8583680);
    float* s      = (float*)(ws + 14973440);
    float* attn   = (float*)(ws + 14978560);

    zero_kernel<<<dim3(128), 256, 0, stream>>>(cls, 64 * 512);
    zero_kernel<<<dim3(512), 256, 0, stream>>>(q, 64 * 2048);

    // 1. cls = x @ W_dml   (fp32 — retrieval precision must match reference)
    gemm_nn_a64_atomic<<<dim3(8, 16), 256, 0, stream>>>(x, Wd, cls, 3072, 512, 512, 3);
    // 2. scores
    score_gemm_nt<<<dim3(94), 256, 0, stream>>>(cls, dml, scores);
    // 3. top-10
    topk_kernel<<<dim3(64), 256, 0, stream>>>(scores, topk);
    // 4. embed
    patch_embed_kernel<<<dim3(64), 384, 0, stream>>>(x, Wp, ct, embed);
    // 5. q = embed @ Wq   (bf16 MFMA, 13-way ksplit, atomic fp32 accumulate)
    gemm_nn_mfma<<<dim3(32, 13), 256, 0, stream>>>(embed, Wq, q, P_DIM, 2048, 2048, 30);
    // 6. t = q @ Wk^T     (bf16 MFMA NT)
    gemm_nt_mfma<<<dim3(390), 256, 0, stream>>>(q, Wk, tmat, 2048, P_DIM);
    // 7. s[b,n]
    sdot_kernel<<<dim3(20, 64), 256, 0, stream>>>(OTin, OTout, topk, tmat, s);
    // 8. softmax
    softmax_kernel<<<dim3(1), 64, 0, stream>>>(s, attn);
    // 9. out
    out_kernel<<<dim3(10, 64), 256, 0, stream>>>(OTin, OTout, topk, attn, out);
}